// Round 1
// 1149.802 us; speedup vs baseline: 1.1048x; 1.1048x over previous
//
#include <hip/hip_runtime.h>

#define B_  512
#define T_  1024
#define F_  128
#define H_  81
#define G3  243
#define GPX 244                 // xg row stride (floats), layout [b][t][GPX]

typedef unsigned short u16;
typedef __attribute__((ext_vector_type(8))) short bf16x8;
typedef __attribute__((ext_vector_type(4))) float f32x4;
typedef __attribute__((ext_vector_type(2))) float f32x2;

__device__ __forceinline__ float bf2f(u16 u) {
    union { unsigned int i; float f; } v; v.i = ((unsigned int)u) << 16; return v.f;
}
__device__ __forceinline__ u16 f2bf(float f) {
    union { float f; unsigned int i; } v; v.f = f;
    unsigned int i = v.i;
    return (u16)((i + 0x7fffu + ((i >> 16) & 1u)) >> 16);
}
__device__ __forceinline__ float sigmoidf_(float x) { return 1.f / (1.f + __expf(-x)); }
__device__ __forceinline__ float tanhf_(float x) {
    float e = __expf(2.f * x);
    return 1.f - 2.f / (e + 1.f);
}
// barrier without vmcnt(0) drain: LDS-correct (lgkmcnt(0) before s_barrier),
// leaves global prefetch loads in flight (m139/AITER technique).
__device__ __forceinline__ void barrier_nodrain() {
    asm volatile("s_waitcnt lgkmcnt(0)\n\ts_barrier" ::: "memory");
}

// ---------------------------------------------------------------------------
// K0: split W_ih fp32 -> bf16 hi/lo.
// ---------------------------------------------------------------------------
__global__ void wsplit_kernel(const float* __restrict__ W,
                              u16* __restrict__ hi, u16* __restrict__ lo)
{
    const int i = blockIdx.x * 256 + threadIdx.x;
    if (i < G3 * F_) {
        const float v = W[i];
        const u16 h = f2bf(v);
        hi[i] = h;
        lo[i] = f2bf(v - bf2f(h));
    }
}

// ---------------------------------------------------------------------------
// K1: xg[b][t][g] = x[b][t]·W_ih[g] + b_ih[g]  (split-bf16 MFMA, 3 terms).
//     Block = (b, 128 t's), 256 thr; wave w owns m-tiles {2w,2w+1}.
//     W staged in two 64-k halves (hi+lo, 62 KB LDS): row = 8 chunks of
//     8 u16, chunk c of row g stored at slot ((c+g)&7) -> conflict-free
//     b128 reads, 16B aligned. 2 blocks/CU co-resident.
// ---------------------------------------------------------------------------
__global__ __launch_bounds__(256, 2) void xg_gemm(const float* __restrict__ x,
                                                  const u16* __restrict__ Whi,
                                                  const u16* __restrict__ Wlo,
                                                  const float* __restrict__ b_ih,
                                                  float* __restrict__ xg)
{
    __shared__ __align__(16) u16 ws_hi[G3][64];
    __shared__ __align__(16) u16 ws_lo[G3][64];

    const int tid  = threadIdx.x;
    const int wave = tid >> 6, lane = tid & 63;
    const int l15  = lane & 15, q = lane >> 4;
    const int b    = blockIdx.x & 511;
    const int t0   = (blockIdx.x >> 9) << 7;

    f32x4 acc[2][16];
#pragma unroll
    for (int mt = 0; mt < 2; ++mt)
#pragma unroll
        for (int gt = 0; gt < 16; ++gt) acc[mt][gt] = (f32x4){0.f, 0.f, 0.f, 0.f};

    for (int half = 0; half < 2; ++half) {
        if (half) __syncthreads();            // protect LDS reuse
        // stage this half: 243 rows x 64 u16, hi then lo (3888 uint4 copies)
#pragma unroll
        for (int it = 0; it < 16; ++it) {
            const int i = it * 256 + tid;
            if (i < 2 * G3 * 8) {
                const bool lo = (i >= G3 * 8);
                const int j = lo ? (i - G3 * 8) : i;
                const int g = j >> 3, c = j & 7;
                const uint4 v = *(const uint4*)((lo ? Wlo : Whi)
                                                + (size_t)g * F_ + half * 64 + c * 8);
                *(uint4*)&((lo ? ws_lo : ws_hi)[g][((c + g) & 7) * 8]) = v;
            }
        }
        __syncthreads();

#pragma unroll
        for (int kcl = 0; kcl < 2; ++kcl) {
            // A fragments (2 m-tiles), fp32 -> bf16 hi/lo split in-register
            bf16x8 aHi[2], aLo[2];
#pragma unroll
            for (int mt = 0; mt < 2; ++mt) {
                const float* xr = x + ((size_t)b * T_ + t0 + (wave * 2 + mt) * 16 + l15) * F_
                                  + half * 64 + kcl * 32 + q * 8;
                float xv[8];
                *(float4*)&xv[0] = *(const float4*)(xr);
                *(float4*)&xv[4] = *(const float4*)(xr + 4);
#pragma unroll
                for (int j = 0; j < 8; ++j) {
                    const u16 h = f2bf(xv[j]);
                    aHi[mt][j] = (short)h;
                    aLo[mt][j] = (short)f2bf(xv[j] - bf2f(h));
                }
            }
#pragma unroll
            for (int gt = 0; gt < 16; ++gt) {
                const int gr  = gt * 16 + l15;
                const int grc = (gr < G3) ? gr : (G3 - 1);
                const int sl  = ((kcl * 4 + q + grc) & 7) * 8;
                const bf16x8 bHi = *(const bf16x8*)&ws_hi[grc][sl];
                const bf16x8 bLo = *(const bf16x8*)&ws_lo[grc][sl];
#pragma unroll
                for (int mt = 0; mt < 2; ++mt) {
                    acc[mt][gt] = __builtin_amdgcn_mfma_f32_16x16x32_bf16(aHi[mt], bHi, acc[mt][gt], 0, 0, 0);
                    acc[mt][gt] = __builtin_amdgcn_mfma_f32_16x16x32_bf16(aHi[mt], bLo, acc[mt][gt], 0, 0, 0);
                    acc[mt][gt] = __builtin_amdgcn_mfma_f32_16x16x32_bf16(aLo[mt], bHi, acc[mt][gt], 0, 0, 0);
                }
            }
        }
    }
    // epilogue: C/D layout col=l15 (g), row=q*4+c (t); [b][t][g] dword stores
#pragma unroll
    for (int gt = 0; gt < 16; ++gt) {
        const int g = gt * 16 + l15;
        if (g < G3) {
            const float bias = b_ih[g];
#pragma unroll
            for (int mt = 0; mt < 2; ++mt) {
                const int trow = t0 + (wave * 2 + mt) * 16 + q * 4;
#pragma unroll
                for (int c = 0; c < 4; ++c)
                    xg[((size_t)b * T_ + trow + c) * GPX + g] = acc[mt][gt][c] + bias;
            }
        }
    }
}

// ---------------------------------------------------------------------------
// K2: GRU recurrence, v2.
//     Old layout (thread = one gate row, full k) re-read all of h per thread:
//     8 waves x 21 ds_read_b128 broadcast = 168 b128/step/CU ~ 2000 cyc at the
//     ~12cyc b128 return-path rate == the measured 1900 cyc/step wall. Also
//     VGPR_Count=60 < the 84 VGPRs of declared weights => weights were NOT
//     ArchVGPR-resident (remat/AGPR round-trips every step).
//     New layout: thread (j,p) owns ALL THREE gate rows of unit j (r,z,n) for
//     one k-third (28 of padded-84 h floats). Same 84-VGPR weight footprint,
//     but h broadcast reads drop 21 -> 7 b128/thread (3x less LDS return
//     traffic/CU). asm "+v" keep-alive pins weights in VGPRs (remat-proof).
//     Partials in part[p][row] (lane-consecutive b32, conflict-free); xr/xz
//     folded into partials pre-barrier; 81 gate threads sum 3 partials/gate,
//     keep h in a register. 2 barriers/step as before. ~120 VGPR, (256,2)
//     keeps 2 blocks/CU co-resident (grid-limited occupancy).
// ---------------------------------------------------------------------------
__global__ __launch_bounds__(256, 2) void gru_kernel(const float* __restrict__ xg,
                                                     const float* __restrict__ W_hh,
                                                     const float* __restrict__ b_hh,
                                                     float* __restrict__ h_out)
{
    __shared__ __align__(16) float h_s[88];          // h padded, 81..87 = 0
    __shared__ float part0[244];                     // k-third 0 partials, [row]
    __shared__ float part1[244];                     // k-third 1
    __shared__ float part2[244];                     // k-third 2
    __shared__ float xn_s[84];                       // xn staging (n-gate x-term)

    const int tid = threadIdx.x, b = blockIdx.x;
    const bool act = tid < G3;
    const int p   = (tid >= 162) ? 2 : ((tid >= 81) ? 1 : 0);
    const int j   = act ? (tid - p * 81) : 0;        // hidden-unit index
    const int k0  = p * 28;                          // k-third base (padded H=84)

    // weights: rows {j, j+81, j+162}, k in [k0, k0+28); zero-padded past H
    f32x2 w2[3][14];
#pragma unroll
    for (int i = 0; i < 3; ++i) {
        const float* wr = W_hh + (size_t)(j + 81 * i) * H_ + k0;
#pragma unroll
        for (int c = 0; c < 14; ++c) {
            const float e0 = (act && (k0 + 2 * c)     < H_) ? wr[2 * c]     : 0.f;
            const float e1 = (act && (k0 + 2 * c + 1) < H_) ? wr[2 * c + 1] : 0.f;
            w2[i][c] = (f32x2){e0, e1};
        }
    }
    // pin weights in ArchVGPRs: opaque to remat, cannot be reloaded per step
#pragma unroll
    for (int i = 0; i < 3; ++i)
#pragma unroll
        for (int c = 0; c < 14; ++c)
            asm volatile("" : "+v"(w2[i][c]));

    // gate-thread constants (tid < 81): biases + register-resident h
    const bool gth = tid < H_;
    const float br = gth ? b_hh[tid]          : 0.f;
    const float bz = gth ? b_hh[H_ + tid]     : 0.f;
    const float bn = gth ? b_hh[2 * H_ + tid] : 0.f;
    float hreg = 0.f;

    if (tid < 88) h_s[tid] = 0.f;
    __syncthreads();

    float* const pp = (p == 0) ? part0 : ((p == 1) ? part1 : part2);

    const float* xp = xg + (size_t)b * T_ * GPX + (act ? tid : 0);
    float xf[4];
#pragma unroll
    for (int u = 0; u < 4; ++u) xf[u] = xp[(size_t)u * GPX];

    for (int t4 = 0; t4 < T_; t4 += 4) {
#pragma unroll
        for (int u = 0; u < 4; ++u) {
            const float xv = xf[u];
            // --- dot: 3 rows x 28 k, 2-way split accumulator chains ---
            f32x2 aA[3], aB[3];
#pragma unroll
            for (int i = 0; i < 3; ++i) { aA[i] = (f32x2){0.f, 0.f}; aB[i] = (f32x2){0.f, 0.f}; }
#pragma unroll
            for (int c = 0; c < 7; ++c) {
                const float4 h4 = ((const float4*)h_s)[p * 7 + c];
                const f32x2 hlo = {h4.x, h4.y}, hhi = {h4.z, h4.w};
#pragma unroll
                for (int i = 0; i < 3; ++i) {
                    aA[i] = __builtin_elementwise_fma(w2[i][2 * c],     hlo, aA[i]);
                    aB[i] = __builtin_elementwise_fma(w2[i][2 * c + 1], hhi, aB[i]);
                }
            }
            const f32x2 t0v = aA[0] + aB[0];
            const f32x2 t1v = aA[1] + aB[1];
            const f32x2 t2v = aA[2] + aB[2];
            float s0 = t0v.x + t0v.y;   // row j       (r)
            float s1 = t1v.x + t1v.y;   // row j+81    (z)
            float s2 = t2v.x + t2v.y;   // row j+162   (n)
            // fold this thread's own x-term into its own row's partial
            // (own row == tid == j+81p; n-row x-term stays separate: xn_s)
            s0 += (p == 0) ? xv : 0.f;
            s1 += (p == 1) ? xv : 0.f;
            if (act) {
                if (p == 2) xn_s[j] = xv;
                pp[j]       = s0;
                pp[j + 81]  = s1;
                pp[j + 162] = s2;
            }
            barrier_nodrain();
            // --- gates: 81 threads, h stays in a register ---
            if (gth) {
                const float prer = part0[tid]       + part1[tid]       + part2[tid]       + br;
                const float prez = part0[tid + 81]  + part1[tid + 81]  + part2[tid + 81]  + bz;
                const float hn   = part0[tid + 162] + part1[tid + 162] + part2[tid + 162] + bn;
                const float rr = sigmoidf_(prer);
                const float zz = sigmoidf_(prez);
                const float nn = tanhf_(fmaf(rr, hn, xn_s[tid]));
                hreg = nn + zz * (hreg - nn);
                h_s[tid] = hreg;
            }
            barrier_nodrain();
            // prefetch 4 steps ahead (clamped; stays in flight across fences)
            const int tn = (t4 + u + 4 < T_) ? (t4 + u + 4) : (T_ - 1);
            xf[u] = xp[(size_t)tn * GPX];
        }
    }

    if (gth) h_out[(size_t)b * H_ + tid] = hreg;
}

// ---------------------------------------------------------------------------
// K3: head. One block, 512 threads (thread = batch row), fp32 throughout.
// ---------------------------------------------------------------------------
__device__ __forceinline__ float block_sum(float v, float* red, int tid) {
#pragma unroll
    for (int off = 32; off; off >>= 1) v += __shfl_down(v, off, 64);
    const int wid = tid >> 6;
    if ((tid & 63) == 0) red[wid] = v;
    __syncthreads();
    if (tid == 0) {
        float s = 0.f;
#pragma unroll
        for (int i = 0; i < 8; ++i) s += red[i];
        red[8] = s;
    }
    __syncthreads();
    const float s = red[8];
    __syncthreads();
    return s;
}

__global__ __launch_bounds__(512) void head_kernel(const float* __restrict__ h_out,
                                                   const float* __restrict__ fc_w,
                                                   const float* __restrict__ fc_b,
                                                   const float* __restrict__ g1,
                                                   const float* __restrict__ beta1,
                                                   const float* __restrict__ fc1_w,
                                                   const float* __restrict__ fc1_b,
                                                   const float* __restrict__ g2,
                                                   const float* __restrict__ beta2,
                                                   const float* __restrict__ fc2_w,
                                                   const float* __restrict__ fc2_b,
                                                   float* __restrict__ out)
{
    __shared__ float red[9];
    const int tid = threadIdx.x;
    const float inv = 1.f / 512.f;

    float hv[H_];
    const float* hp = h_out + (size_t)tid * H_;
#pragma unroll
    for (int c = 0; c < H_; ++c) hv[c] = hp[c];

    float o[8];
#pragma unroll
    for (int j = 0; j < 8; ++j) {
        float s = fc_b[j];
        for (int c = 0; c < H_; ++c) s += hv[c] * fc_w[j * H_ + c];
        o[j] = s * sigmoidf_(s);
    }
#pragma unroll
    for (int j = 0; j < 8; ++j) {
        const float mu = block_sum(o[j], red, tid) * inv;
        const float m2 = block_sum(o[j] * o[j], red, tid) * inv;
        o[j] = (o[j] - mu) * rsqrtf(m2 - mu * mu + 1e-5f) * g1[j] + beta1[j];
    }
    float p[4];
#pragma unroll
    for (int i = 0; i < 4; ++i) {
        float s = fc1_b[i];
#pragma unroll
        for (int j = 0; j < 8; ++j) s += o[j] * fc1_w[i * 8 + j];
        p[i] = s * sigmoidf_(s);
    }
#pragma unroll
    for (int i = 0; i < 4; ++i) {
        const float mu = block_sum(p[i], red, tid) * inv;
        const float m2 = block_sum(p[i] * p[i], red, tid) * inv;
        p[i] = (p[i] - mu) * rsqrtf(m2 - mu * mu + 1e-5f) * g2[i] + beta2[i];
    }
    float res = fc2_b[0];
#pragma unroll
    for (int i = 0; i < 4; ++i) res += p[i] * fc2_w[i];
    out[tid] = res;
}

// ---------------------------------------------------------------------------
extern "C" void kernel_launch(void* const* d_in, const int* in_sizes, int n_in,
                              void* d_out, int out_size, void* d_ws, size_t ws_size,
                              hipStream_t stream)
{
    const float* x     = (const float*)d_in[0];
    const float* W_ih  = (const float*)d_in[1];
    const float* W_hh  = (const float*)d_in[2];
    const float* b_ih  = (const float*)d_in[3];
    const float* b_hh  = (const float*)d_in[4];

    float* xg    = (float*)d_ws;                        // 512*1024*244*4 = 488 MiB
    float* h_out = xg + (size_t)B_ * T_ * GPX;
    u16*   Whi   = (u16*)(h_out + B_ * H_);
    u16*   Wlo   = Whi + G3 * F_;

    wsplit_kernel<<<dim3((G3 * F_ + 255) / 256), dim3(256), 0, stream>>>(W_ih, Whi, Wlo);
    xg_gemm<<<dim3(512 * 8), dim3(256), 0, stream>>>(x, Whi, Wlo, b_ih, xg);
    gru_kernel<<<dim3(B_), dim3(256), 0, stream>>>(xg, W_hh, b_hh, h_out);
    head_kernel<<<dim3(1), dim3(512), 0, stream>>>(h_out,
        (const float*)d_in[5], (const float*)d_in[6], (const float*)d_in[7],
        (const float*)d_in[8], (const float*)d_in[9], (const float*)d_in[10],
        (const float*)d_in[11], (const float*)d_in[12], (const float*)d_in[13],
        (const float*)d_in[14], (float*)d_out);
}